// Round 8
// baseline (1182.497 us; speedup 1.0000x reference)
//
#include <hip/hip_runtime.h>
#include <hip/hip_bf16.h>
#include <math.h>

#define BQ 2
#define SEQ 2048
#define NDIM 1024
#define HEADS 16
#define DH 64
#define NSTEPS 8
#define SCALE 22.60530911f      /* sqrt(511) */
#define SCALE_HEAD 5.567764363f /* sqrt(31)  */
#define INV_SCALE2 (1.0f/511.0f)
#define EXS 8.0325527f          /* SCALE_HEAD * log2(e) */

typedef unsigned short u16;
typedef unsigned char u8;
typedef long long i64;
typedef __attribute__((ext_vector_type(8))) short bf16x8;   // 8 bf16 = 4 VGPR
typedef __attribute__((ext_vector_type(4))) float floatx4;  // MFMA 16x16 acc

__device__ __forceinline__ float bf2f(u16 u) {
  union { unsigned int i; float f; } v; v.i = ((unsigned int)u) << 16; return v.f;
}
__device__ __forceinline__ u16 f2bf(float f) {
  union { float f; unsigned int i; } v; v.f = f;
  unsigned int x = v.i;
  return (u16)((x + 0x7fffu + ((x >> 16) & 1u)) >> 16);
}

// packed fp8 conversion via HW cvt (gfx950 native fp8 = OCP e4m3fn)
__device__ __forceinline__ int pk4_fp8(float a, float b, float c, float d) {
  int p = 0;
  p = __builtin_amdgcn_cvt_pk_fp8_f32(a, b, p, false);
  p = __builtin_amdgcn_cvt_pk_fp8_f32(c, d, p, true);
  return p;
}

// async global->LDS, 16B per lane; LDS dest = wave-uniform base + lane*16
#define GLD16(gp, lp) __builtin_amdgcn_global_load_lds( \
    (__attribute__((address_space(1))) void*)(gp),      \
    (__attribute__((address_space(3))) void*)(lp), 16, 0, 0)

// ---------------- dtype probe: flag=1 if input is fp32 ----------------
__global__ void k_flag0(int* flag) { if (threadIdx.x == 0 && blockIdx.x == 0) *flag = 0; }

__global__ __launch_bounds__(256) void k_probe(const u16* __restrict__ x, int* __restrict__ flag) {
  int i = blockIdx.x * 256 + threadIdx.x;
  float v = bf2f(x[i]);
  if (!(fabsf(v) <= 1e4f)) atomicOr(flag, 1);
}

__global__ __launch_bounds__(256) void k_convert(const void* __restrict__ in, u16* __restrict__ outb,
                                                 const int* __restrict__ flag, int n) {
  int i = blockIdx.x * 256 + threadIdx.x;
  if (i >= n) return;
  if (*flag) outb[i] = f2bf(((const float*)in)[i]);
  else       outb[i] = ((const u16*)in)[i];
}

// ---------------- normalize + scale x -> xs (bf16) ----------------
__global__ __launch_bounds__(256) void k_norm_scale(const u16* __restrict__ x, u16* __restrict__ xs) {
  __shared__ float red[256];
  int row = blockIdx.x;
  const u16* xr = x + (size_t)row * NDIM;
  u16* orow = xs + (size_t)row * NDIM;
  int t = threadIdx.x;
  float vals[4]; float s = 0.f;
#pragma unroll
  for (int e = 0; e < 4; e++) { float v = bf2f(xr[t + 256*e]); vals[e] = v; s += v*v; }
  red[t] = s; __syncthreads();
  for (int o = 128; o > 0; o >>= 1) { if (t < o) red[t] += red[t+o]; __syncthreads(); }
  float sc = SCALE / fmaxf(sqrtf(red[0]), 1e-12f);
#pragma unroll
  for (int e = 0; e < 4; e++) orow[t + 256*e] = f2bf(vals[e] * sc);
}

// ---------------- MFMA GEMM (bf16): C[m,n] = act(sum_k A[m,k] W[n,k]) (+addsrc) ----------------
template<int OUT_BF16, int GELU, int ADDSRC>
__global__ __launch_bounds__(256) void k_gemm(const u16* __restrict__ A, const u16* __restrict__ W,
                                              float* __restrict__ Cf, u16* __restrict__ Cb,
                                              const u16* __restrict__ addsrc, int M, int N, int K) {
  __shared__ __align__(16) u16 As[128*32];
  __shared__ __align__(16) u16 Bs[128*32];
  int t = threadIdx.x;
  int w = t >> 6, L = t & 63;
  int quad = L >> 4, l15 = L & 15;
  int wr = w >> 1, wc = w & 1;
  int bm = blockIdx.x * 128, bn = blockIdx.y * 128;
  int srow = L >> 2, scol = (L & 3) * 8;
  floatx4 acc[4][4];
#pragma unroll
  for (int i = 0; i < 4; i++)
#pragma unroll
    for (int j = 0; j < 4; j++) acc[i][j] = (floatx4){0.f,0.f,0.f,0.f};

  for (int k0 = 0; k0 < K; k0 += 32) {
#pragma unroll
    for (int c = 0; c < 2; c++) {
      int r = c*64 + w*16 + srow;
      GLD16(A + (size_t)(bm + r)*K + k0 + scol, &As[(c*64 + w*16)*32]);
      GLD16(W + (size_t)(bn + r)*K + k0 + scol, &Bs[(c*64 + w*16)*32]);
    }
    __syncthreads();
    bf16x8 af[4], bfr[4];
#pragma unroll
    for (int mt = 0; mt < 4; mt++) af[mt]  = *(const bf16x8*)&As[(wr*64 + mt*16 + l15)*32 + quad*8];
#pragma unroll
    for (int nt = 0; nt < 4; nt++) bfr[nt] = *(const bf16x8*)&Bs[(wc*64 + nt*16 + l15)*32 + quad*8];
#pragma unroll
    for (int mt = 0; mt < 4; mt++)
#pragma unroll
      for (int nt = 0; nt < 4; nt++)
        acc[mt][nt] = __builtin_amdgcn_mfma_f32_16x16x32_bf16(af[mt], bfr[nt], acc[mt][nt], 0, 0, 0);
    __syncthreads();
  }
#pragma unroll
  for (int mt = 0; mt < 4; mt++)
#pragma unroll
    for (int reg = 0; reg < 4; reg++) {
      int m = bm + wr*64 + mt*16 + quad*4 + reg;
      size_t rowoff = (size_t)m * N;
#pragma unroll
      for (int nt = 0; nt < 4; nt++) {
        int n = bn + wc*64 + nt*16 + l15;
        float v = acc[mt][nt][reg];
        if (GELU) v = 0.5f * v * (1.0f + erff(v * 0.70710678118f));
        if (ADDSRC) v += bf2f(addsrc[rowoff + n]);
        if (OUT_BF16) Cb[rowoff + n] = f2bf(v);
        else Cf[rowoff + n] = v;
      }
    }
}

// ---------------- per-head normalize q,k -> [B,H,N,DH] bf16 ----------------
__global__ __launch_bounds__(64) void k_headnorm(const u16* __restrict__ qkraw,
                                                 u16* __restrict__ qn, u16* __restrict__ kn) {
  int blk = blockIdx.x;
  int h = blk & (HEADS-1); int bi = blk >> 4;
  int b = bi >> 11, i = bi & (SEQ-1);
  int d = threadIdx.x;
  const u16* base = qkraw + (size_t)bi * (2*NDIM);
  float qv = bf2f(base[h*DH + d]);
  float kv = bf2f(base[NDIM + h*DH + d]);
  float qs = qv*qv, ks = kv*kv;
#pragma unroll
  for (int o = 32; o > 0; o >>= 1) { qs += __shfl_xor(qs, o); ks += __shfl_xor(ks, o); }
  size_t oidx = ((size_t)(b*HEADS + h) * SEQ + i) * DH + d;
  qn[oidx] = f2bf(qv / fmaxf(sqrtf(qs), 1e-12f));
  kn[oidx] = f2bf(kv / fmaxf(sqrtf(ks), 1e-12f));
}

// ---------------- MFMA attn (fp8 out, x256 scaled): swapped operands C[j][i] ----------------
// Block = 16 q-rows (i) x 2048 j. No max pass (|sim| <= 5.57). LDS bounce for coalesced stores.
__global__ __launch_bounds__(256) void k_attn(const u16* __restrict__ qb, const u16* __restrict__ kb,
                                              u8* __restrict__ attn, int bh0) {
  __shared__ __align__(16) u8 sim[16][2064];   // [i][j], +16B pad
  __shared__ float reds[4][16];
  int t = threadIdx.x;
  int w = t >> 6, L = t & 63;
  int quad = L >> 4, l15 = L & 15;
  int bh_local = blockIdx.x >> 7;              // 128 i-tiles per bh
  int bh = bh0 + bh_local;
  int i0 = (blockIdx.x & 127) * 16;
  // B-operand: Q row i = i0 + l15
  const u16* qrow = qb + ((size_t)bh*SEQ + i0 + l15)*DH + quad*8;
  bf16x8 b0 = *(const bf16x8*)qrow;
  bf16x8 b1 = *(const bf16x8*)(qrow + 32);
  const u16* kbase = kb + (size_t)bh*SEQ*DH;
  floatx4 acc[32];
  float s = 0.f;
#pragma unroll
  for (int tt = 0; tt < 32; tt++) {
    int j = w*512 + tt*16 + l15;               // A-operand row = j
    const u16* krow = kbase + (size_t)j*DH + quad*8;
    bf16x8 a0 = *(const bf16x8*)krow;
    bf16x8 a1 = *(const bf16x8*)(krow + 32);
    floatx4 c = (floatx4){0.f,0.f,0.f,0.f};
    c = __builtin_amdgcn_mfma_f32_16x16x32_bf16(a0, b0, c, 0, 0, 0);
    c = __builtin_amdgcn_mfma_f32_16x16x32_bf16(a1, b1, c, 0, 0, 0);
#pragma unroll
    for (int r = 0; r < 4; r++) { float e = exp2f(EXS * c[r]); c[r] = e; s += e; }
    acc[tt] = c;
  }
  // sum over j for fixed i=l15: reduce across quads, then across waves
  s += __shfl_xor(s, 16); s += __shfl_xor(s, 32);
  if (quad == 0) reds[w][l15] = s;
  __syncthreads();
  float inv = 256.0f / (reds[0][l15] + reds[1][l15] + reds[2][l15] + reds[3][l15]);
  // pack 4 consecutive j (regs) into uint32, write LDS [i][j]
#pragma unroll
  for (int tt = 0; tt < 32; tt++) {
    int p = pk4_fp8(acc[tt][0]*inv, acc[tt][1]*inv, acc[tt][2]*inv, acc[tt][3]*inv);
    *(int*)&sim[l15][w*512 + tt*16 + quad*4] = p;
  }
  __syncthreads();
  // coalesced store: 16 rows x 2048 B (each thread copies 8 x 16B, stride 256B)
  int row = t >> 4, ch = t & 15;
  const uint4* srow = (const uint4*)&sim[row][0];
  uint4* drow = (uint4*)(attn + ((size_t)bh_local*SEQ + i0 + row)*SEQ);
#pragma unroll
  for (int k = 0; k < 8; k++) drow[ch + 16*k] = srow[ch + 16*k];
}

// ---------------- m0 init (fp8 0.5 = 0x30) ----------------
__global__ void k_minit8(unsigned int* __restrict__ m, unsigned int val, int nwords) {
  int i = blockIdx.x*256 + threadIdx.x; if (i < nwords) m[i] = val;
}

__global__ void k_zero(float* __restrict__ o, int n) {
  int i = blockIdx.x*256 + threadIdx.x; if (i < n) o[i] = 0.f;
}

// ---------------- fp8 MFMA mean-field step, barrier-free ----------------
// attn fp8 [i][j] (x256), m fp8 transposed [bh][d][i]. Block: 128 i x 64 d.
// All fragments loaded DIRECTLY global->VGPR (rows are contiguous 8B runs; the 4
// quads x 4 consecutive j-iters consume full 128B lines via L1). No LDS, no barriers.
template<int LAST>
__global__ __launch_bounds__(256) void k_step(const u8* __restrict__ attn, const u8* __restrict__ mT_in,
                                              const float* __restrict__ xf, u8* __restrict__ mT_out,
                                              float* __restrict__ out, int bh0) {
  int t = threadIdx.x;
  int w = t >> 6, L = t & 63;
  int quad = L >> 4, l15 = L & 15;
  int bh_local = blockIdx.x >> 4;            // 16 i-tiles per bh
  int bh = bh0 + bh_local;
  int i0 = (blockIdx.x & 15) * 128;
  int b = bh >> 4, h = bh & (HEADS-1);
  const u8* arow0 = attn + ((size_t)bh_local*SEQ + i0 + w*32 + l15)*SEQ + quad*8;
  const u8* arow1 = arow0 + (size_t)16*SEQ;
  const u8* mrow  = mT_in + ((size_t)bh*DH + l15)*SEQ + quad*8;
  floatx4 acc[2][4];
#pragma unroll
  for (int i = 0; i < 2; i++)
#pragma unroll
    for (int j = 0; j < 4; j++) acc[i][j] = (floatx4){0.f,0.f,0.f,0.f};

#pragma unroll 4
  for (int j0 = 0; j0 < SEQ; j0 += 32) {
    i64 a0 = *(const i64*)(arow0 + j0);
    i64 a1 = *(const i64*)(arow1 + j0);
#pragma unroll
    for (int nt = 0; nt < 4; nt++) {
      i64 bf = *(const i64*)(mrow + (size_t)nt*16*SEQ + j0);
      acc[0][nt] = __builtin_amdgcn_mfma_f32_16x16x32_fp8_fp8(a0, bf, acc[0][nt], 0, 0, 0);
      acc[1][nt] = __builtin_amdgcn_mfma_f32_16x16x32_fp8_fp8(a1, bf, acc[1][nt], 0, 0, 0);
    }
  }
  const float rs = 1.0f/256.0f;
#pragma unroll
  for (int mt = 0; mt < 2; mt++) {
    int ibase = i0 + w*32 + mt*16 + quad*4;
    float th[4][4]; float invr[4];
#pragma unroll
    for (int reg = 0; reg < 4; reg++) {
      size_t xoff = ((size_t)b*SEQ + ibase + reg)*NDIM + h*DH + l15;
      float s = 0.f;
#pragma unroll
      for (int nt = 0; nt < 4; nt++) {
        float v = acc[mt][nt][reg]*rs + xf[xoff + nt*16];
        th[nt][reg] = v; s += v*v;
      }
      s += __shfl_xor(s, 1); s += __shfl_xor(s, 2); s += __shfl_xor(s, 4); s += __shfl_xor(s, 8);
      float tt2 = 0.5f*(1.0f + sqrtf(1.0f + s * INV_SCALE2));
      invr[reg] = 1.0f/(2.0f*tt2);
    }
    if (LAST) {
#pragma unroll
      for (int reg = 0; reg < 4; reg++) {
        size_t ooff = ((size_t)b*SEQ + ibase + reg)*NDIM + h*DH + l15;
#pragma unroll
        for (int nt = 0; nt < 4; nt++) out[ooff + nt*16] = th[nt][reg]*invr[reg];
      }
    } else {
#pragma unroll
      for (int nt = 0; nt < 4; nt++) {
        int p = pk4_fp8(th[nt][0]*invr[0], th[nt][1]*invr[1],
                        th[nt][2]*invr[2], th[nt][3]*invr[3]);
        *(int*)&mT_out[((size_t)bh*DH + nt*16 + l15)*SEQ + ibase] = p;
      }
    }
  }
}

extern "C" void kernel_launch(void* const* d_in, const int* in_sizes, int n_in,
                              void* d_out, int out_size, void* d_ws, size_t ws_size,
                              hipStream_t stream) {
  const void* x    = d_in[0];
  const void* w_qk = d_in[1];
  const void* w1   = d_in[2];
  const void* w2   = d_in[3];
  float* out = (float*)d_out;

  const size_t E = (size_t)BQ*SEQ*NDIM;     // 4,194,304
  const int NW_QK = 2*NDIM*NDIM;
  const int NW1   = 4*NDIM*NDIM;
  const int NW2   = 4*NDIM*NDIM;

  char* ws = (char*)d_ws;
  size_t off = 0;
  auto alloc = [&](size_t bytes) { void* p = ws + off; off += (bytes + 255) & ~255ull; return p; };
  int*  flag = (int*)alloc(256);
  u16*  xs  = (u16*)alloc(E*2);             // scaled-normalized x (bf16)
  u16*  qb  = (u16*)alloc(E*2);             // q normalized [B,H,N,DH] bf16
  u16*  kb  = (u16*)alloc(E*2);
  float* xf = (float*)alloc(E*4);           // external field fp32
  u8*   mT  = (u8*)alloc(E*2);              // two fp8 m-buffers [B,H,DH,N]
  u8*   mTa = mT;
  u8*   mTb = mT + E;

  char* S = ws + off;
  size_t availS = (ws_size > off) ? ws_size - off : 0;
  // S-region temporal plan: [wqkb|qkraw] -> [.|.|w1b|w2b|hbuf] -> [attn chunk fp8]
  u16* wqkb  = (u16*)(S);
  u16* qkraw = (u16*)(S + 4194304);
  u16* w1b   = (u16*)(S + 20971520);
  u16* w2b   = (u16*)(S + 29360128);
  u16* hbuf  = (u16*)(S + 37748736);
  u8*  attn  = (u8*)(S);
  u16* xb    = (u16*)mT;                     // alias (2E bytes): dead before k_minit8

  const int rcs[6] = {4096, 2048, 1024, 512, 256, 128};
  int RC = 0;
  for (int i = 0; i < 6; i++)
    if (37748736ull + (size_t)rcs[i]*4096*2 <= availS) { RC = rcs[i]; break; }
  const int chs[6] = {32, 16, 8, 4, 2, 1};
  int CH = 0;
  for (int i = 0; i < 6; i++)
    if ((size_t)chs[i]*SEQ*SEQ <= availS) { CH = chs[i]; break; }
  if (RC == 0 || CH == 0) {
    k_zero<<<(out_size+255)/256, 256, 0, stream>>>(out, out_size);
    return;
  }

  const int M = BQ*SEQ;  // 4096

  // dtype probe + canonical bf16 conversion
  k_flag0<<<1, 64, 0, stream>>>(flag);
  k_probe<<<256, 256, 0, stream>>>((const u16*)x, flag);
  k_convert<<<(int)(E/256), 256, 0, stream>>>(x, xb, flag, (int)E);
  k_convert<<<NW_QK/256, 256, 0, stream>>>(w_qk, wqkb, flag, NW_QK);
  k_convert<<<NW1/256, 256, 0, stream>>>(w1, w1b, flag, NW1);
  k_convert<<<NW2/256, 256, 0, stream>>>(w2, w2b, flag, NW2);

  k_norm_scale<<<M, 256, 0, stream>>>(xb, xs);
  { dim3 g(M/128, 2048/128); k_gemm<1,0,0><<<g, 256, 0, stream>>>(xs, wqkb, nullptr, qkraw, nullptr, M, 2048, 1024); }
  k_headnorm<<<M*HEADS, 64, 0, stream>>>(qkraw, qb, kb);

  for (int c = 0; c < M/RC; c++) {
    const u16* xsc = xs + (size_t)c*RC*NDIM;
    { dim3 g(RC/128, 4096/128); k_gemm<1,1,0><<<g, 256, 0, stream>>>(xsc, w1b, nullptr, hbuf, nullptr, RC, 4096, 1024); }
    { dim3 g(RC/128, 1024/128); k_gemm<0,0,1><<<g, 256, 0, stream>>>(hbuf, w2b, xf + (size_t)c*RC*NDIM, nullptr, xsc, RC, 1024, 4096); }
  }

  // m0 = 1/(2*t0) = 0.4853 -> e4m3 RNE -> 0.5 = 0x30
  k_minit8<<<(int)(E/4/256), 256, 0, stream>>>((unsigned int*)mTa, 0x30303030u, (int)(E/4));

  for (int c0 = 0; c0 < BQ*HEADS; c0 += CH) {
    k_attn<<<CH*128, 256, 0, stream>>>(qb, kb, attn, c0);
    for (int s = 0; s < NSTEPS; s++) {
      u8* src = (s & 1) ? mTb : mTa;
      u8* dst = (s & 1) ? mTa : mTb;
      if (s == NSTEPS-1)
        k_step<1><<<CH*16, 256, 0, stream>>>(attn, src, xf, nullptr, out, c0);
      else
        k_step<0><<<CH*16, 256, 0, stream>>>(attn, src, xf, dst, nullptr, c0);
    }
  }
}

// Round 9
// 777.129 us; speedup vs baseline: 1.5216x; 1.5216x over previous
//
#include <hip/hip_runtime.h>
#include <hip/hip_bf16.h>
#include <math.h>

#define BQ 2
#define SEQ 2048
#define NDIM 1024
#define HEADS 16
#define DH 64
#define NSTEPS 8
#define SCALE 22.60530911f      /* sqrt(511) */
#define SCALE_HEAD 5.567764363f /* sqrt(31)  */
#define INV_SCALE2 (1.0f/511.0f)
#define EXS 8.0325527f          /* SCALE_HEAD * log2(e) */

typedef unsigned short u16;
typedef unsigned char u8;
typedef long long i64;
typedef __attribute__((ext_vector_type(8))) short bf16x8;   // 8 bf16 = 4 VGPR
typedef __attribute__((ext_vector_type(4))) float floatx4;  // MFMA 16x16 acc

__device__ __forceinline__ float bf2f(u16 u) {
  union { unsigned int i; float f; } v; v.i = ((unsigned int)u) << 16; return v.f;
}
__device__ __forceinline__ u16 f2bf(float f) {
  union { float f; unsigned int i; } v; v.f = f;
  unsigned int x = v.i;
  return (u16)((x + 0x7fffu + ((x >> 16) & 1u)) >> 16);
}

// packed fp8 conversion via HW cvt (gfx950 native fp8 = OCP e4m3fn; validated r8: absmax unchanged)
__device__ __forceinline__ int pk4_fp8(float a, float b, float c, float d) {
  int p = 0;
  p = __builtin_amdgcn_cvt_pk_fp8_f32(a, b, p, false);
  p = __builtin_amdgcn_cvt_pk_fp8_f32(c, d, p, true);
  return p;
}

// async global->LDS, 16B per lane; LDS dest = wave-uniform base + lane*16
#define GLD16(gp, lp) __builtin_amdgcn_global_load_lds( \
    (__attribute__((address_space(1))) void*)(gp),      \
    (__attribute__((address_space(3))) void*)(lp), 16, 0, 0)

// ---------------- dtype probe: flag=1 if input is fp32 ----------------
__global__ void k_flag0(int* flag) { if (threadIdx.x == 0 && blockIdx.x == 0) *flag = 0; }

__global__ __launch_bounds__(256) void k_probe(const u16* __restrict__ x, int* __restrict__ flag) {
  int i = blockIdx.x * 256 + threadIdx.x;
  float v = bf2f(x[i]);
  if (!(fabsf(v) <= 1e4f)) atomicOr(flag, 1);
}

__global__ __launch_bounds__(256) void k_convert(const void* __restrict__ in, u16* __restrict__ outb,
                                                 const int* __restrict__ flag, int n) {
  int i = blockIdx.x * 256 + threadIdx.x;
  if (i >= n) return;
  if (*flag) outb[i] = f2bf(((const float*)in)[i]);
  else       outb[i] = ((const u16*)in)[i];
}

// ---------------- normalize + scale x -> xs (bf16) ----------------
__global__ __launch_bounds__(256) void k_norm_scale(const u16* __restrict__ x, u16* __restrict__ xs) {
  __shared__ float red[256];
  int row = blockIdx.x;
  const u16* xr = x + (size_t)row * NDIM;
  u16* orow = xs + (size_t)row * NDIM;
  int t = threadIdx.x;
  float vals[4]; float s = 0.f;
#pragma unroll
  for (int e = 0; e < 4; e++) { float v = bf2f(xr[t + 256*e]); vals[e] = v; s += v*v; }
  red[t] = s; __syncthreads();
  for (int o = 128; o > 0; o >>= 1) { if (t < o) red[t] += red[t+o]; __syncthreads(); }
  float sc = SCALE / fmaxf(sqrtf(red[0]), 1e-12f);
#pragma unroll
  for (int e = 0; e < 4; e++) orow[t + 256*e] = f2bf(vals[e] * sc);
}

// ---------------- MFMA GEMM (bf16): C[m,n] = act(sum_k A[m,k] W[n,k]) (+addsrc) ----------------
template<int OUT_BF16, int GELU, int ADDSRC>
__global__ __launch_bounds__(256) void k_gemm(const u16* __restrict__ A, const u16* __restrict__ W,
                                              float* __restrict__ Cf, u16* __restrict__ Cb,
                                              const u16* __restrict__ addsrc, int M, int N, int K) {
  __shared__ __align__(16) u16 As[128*32];
  __shared__ __align__(16) u16 Bs[128*32];
  int t = threadIdx.x;
  int w = t >> 6, L = t & 63;
  int quad = L >> 4, l15 = L & 15;
  int wr = w >> 1, wc = w & 1;
  int bm = blockIdx.x * 128, bn = blockIdx.y * 128;
  int srow = L >> 2, scol = (L & 3) * 8;
  floatx4 acc[4][4];
#pragma unroll
  for (int i = 0; i < 4; i++)
#pragma unroll
    for (int j = 0; j < 4; j++) acc[i][j] = (floatx4){0.f,0.f,0.f,0.f};

  for (int k0 = 0; k0 < K; k0 += 32) {
#pragma unroll
    for (int c = 0; c < 2; c++) {
      int r = c*64 + w*16 + srow;
      GLD16(A + (size_t)(bm + r)*K + k0 + scol, &As[(c*64 + w*16)*32]);
      GLD16(W + (size_t)(bn + r)*K + k0 + scol, &Bs[(c*64 + w*16)*32]);
    }
    __syncthreads();
    bf16x8 af[4], bfr[4];
#pragma unroll
    for (int mt = 0; mt < 4; mt++) af[mt]  = *(const bf16x8*)&As[(wr*64 + mt*16 + l15)*32 + quad*8];
#pragma unroll
    for (int nt = 0; nt < 4; nt++) bfr[nt] = *(const bf16x8*)&Bs[(wc*64 + nt*16 + l15)*32 + quad*8];
#pragma unroll
    for (int mt = 0; mt < 4; mt++)
#pragma unroll
      for (int nt = 0; nt < 4; nt++)
        acc[mt][nt] = __builtin_amdgcn_mfma_f32_16x16x32_bf16(af[mt], bfr[nt], acc[mt][nt], 0, 0, 0);
    __syncthreads();
  }
#pragma unroll
  for (int mt = 0; mt < 4; mt++)
#pragma unroll
    for (int reg = 0; reg < 4; reg++) {
      int m = bm + wr*64 + mt*16 + quad*4 + reg;
      size_t rowoff = (size_t)m * N;
#pragma unroll
      for (int nt = 0; nt < 4; nt++) {
        int n = bn + wc*64 + nt*16 + l15;
        float v = acc[mt][nt][reg];
        if (GELU) v = 0.5f * v * (1.0f + erff(v * 0.70710678118f));
        if (ADDSRC) v += bf2f(addsrc[rowoff + n]);
        if (OUT_BF16) Cb[rowoff + n] = f2bf(v);
        else Cf[rowoff + n] = v;
      }
    }
}

// ---------------- per-head normalize q,k -> [B,H,N,DH] bf16 ----------------
__global__ __launch_bounds__(64) void k_headnorm(const u16* __restrict__ qkraw,
                                                 u16* __restrict__ qn, u16* __restrict__ kn) {
  int blk = blockIdx.x;
  int h = blk & (HEADS-1); int bi = blk >> 4;
  int b = bi >> 11, i = bi & (SEQ-1);
  int d = threadIdx.x;
  const u16* base = qkraw + (size_t)bi * (2*NDIM);
  float qv = bf2f(base[h*DH + d]);
  float kv = bf2f(base[NDIM + h*DH + d]);
  float qs = qv*qv, ks = kv*kv;
#pragma unroll
  for (int o = 32; o > 0; o >>= 1) { qs += __shfl_xor(qs, o); ks += __shfl_xor(ks, o); }
  size_t oidx = ((size_t)(b*HEADS + h) * SEQ + i) * DH + d;
  qn[oidx] = f2bf(qv / fmaxf(sqrtf(qs), 1e-12f));
  kn[oidx] = f2bf(kv / fmaxf(sqrtf(ks), 1e-12f));
}

// ---------------- MFMA attn (fp8 out, x256 scaled): swapped operands C[j][i] ----------------
__global__ __launch_bounds__(256) void k_attn(const u16* __restrict__ qb, const u16* __restrict__ kb,
                                              u8* __restrict__ attn, int bh0) {
  __shared__ __align__(16) u8 sim[16][2064];   // [i][j], +16B pad
  __shared__ float reds[4][16];
  int t = threadIdx.x;
  int w = t >> 6, L = t & 63;
  int quad = L >> 4, l15 = L & 15;
  int bh_local = blockIdx.x >> 7;              // 128 i-tiles per bh
  int bh = bh0 + bh_local;
  int i0 = (blockIdx.x & 127) * 16;
  const u16* qrow = qb + ((size_t)bh*SEQ + i0 + l15)*DH + quad*8;
  bf16x8 b0 = *(const bf16x8*)qrow;
  bf16x8 b1 = *(const bf16x8*)(qrow + 32);
  const u16* kbase = kb + (size_t)bh*SEQ*DH;
  floatx4 acc[32];
  float s = 0.f;
#pragma unroll
  for (int tt = 0; tt < 32; tt++) {
    int j = w*512 + tt*16 + l15;               // A-operand row = j
    const u16* krow = kbase + (size_t)j*DH + quad*8;
    bf16x8 a0 = *(const bf16x8*)krow;
    bf16x8 a1 = *(const bf16x8*)(krow + 32);
    floatx4 c = (floatx4){0.f,0.f,0.f,0.f};
    c = __builtin_amdgcn_mfma_f32_16x16x32_bf16(a0, b0, c, 0, 0, 0);
    c = __builtin_amdgcn_mfma_f32_16x16x32_bf16(a1, b1, c, 0, 0, 0);
#pragma unroll
    for (int r = 0; r < 4; r++) { float e = exp2f(EXS * c[r]); c[r] = e; s += e; }
    acc[tt] = c;
  }
  s += __shfl_xor(s, 16); s += __shfl_xor(s, 32);
  if (quad == 0) reds[w][l15] = s;
  __syncthreads();
  float inv = 256.0f / (reds[0][l15] + reds[1][l15] + reds[2][l15] + reds[3][l15]);
#pragma unroll
  for (int tt = 0; tt < 32; tt++) {
    int p = pk4_fp8(acc[tt][0]*inv, acc[tt][1]*inv, acc[tt][2]*inv, acc[tt][3]*inv);
    *(int*)&sim[l15][w*512 + tt*16 + quad*4] = p;
  }
  __syncthreads();
  int row = t >> 4, ch = t & 15;
  const uint4* srow = (const uint4*)&sim[row][0];
  uint4* drow = (uint4*)(attn + ((size_t)bh_local*SEQ + i0 + row)*SEQ);
#pragma unroll
  for (int k = 0; k < 8; k++) drow[ch + 16*k] = srow[ch + 16*k];
}

__global__ void k_zero(float* __restrict__ o, int n) {
  int i = blockIdx.x*256 + threadIdx.x; if (i < n) o[i] = 0.f;
}

// ---------------- step-0 shortcut: m1 = mag(xf + m0v)  (attn@m0 == m0v exactly) ----------------
// writes fp8 mT [bh][d][i]; block = one bh x 64 i-rows
__global__ __launch_bounds__(256) void k_step0(const float* __restrict__ xf, u8* __restrict__ mT,
                                               float m0v) {
  __shared__ u8 tile[64][68];   // [d][i-col], +4 pad
  int bh = blockIdx.x >> 5;     // 32 i-tiles per bh
  int i0 = (blockIdx.x & 31) * 64;
  int b = bh >> 4, h = bh & (HEADS-1);
  int t = threadIdx.x;
  int row = t >> 2, part = t & 3;          // i-row in tile, 16-float d-part
  const float* xr = xf + ((size_t)b*SEQ + i0 + row)*NDIM + h*DH + part*16;
  float v[16]; float s = 0.f;
#pragma unroll
  for (int e = 0; e < 16; e++) { float u = xr[e] + m0v; v[e] = u; s += u*u; }
  s += __shfl_xor(s, 1); s += __shfl_xor(s, 2);
  float t2 = 0.5f*(1.0f + sqrtf(1.0f + s * INV_SCALE2));
  float inv = 1.0f/(2.0f*t2);
#pragma unroll
  for (int e = 0; e < 16; e += 4) {
    int p = pk4_fp8(v[e]*inv, v[e+1]*inv, v[e+2]*inv, v[e+3]*inv);
    tile[part*16 + e + 0][row] = (u8)(p & 255);
    tile[part*16 + e + 1][row] = (u8)((p >> 8) & 255);
    tile[part*16 + e + 2][row] = (u8)((p >> 16) & 255);
    tile[part*16 + e + 3][row] = (u8)((p >> 24) & 255);
  }
  __syncthreads();
  int d = t >> 2, c = t & 3;
  *(uint4*)&mT[((size_t)bh*DH + d)*SEQ + i0 + c*16] = *(const uint4*)&tile[d][c*16];
}

// ---------------- fp8 MFMA mean-field step (LDS-staged, i-tile=64) ----------------
// attn fp8 [i][j] (x256), m fp8 transposed [bh][d][i]. Block: 64 i x 64 d, BK=32.
template<int LAST>
__global__ __launch_bounds__(256) void k_step(const u8* __restrict__ attn, const u8* __restrict__ mT_in,
                                              const float* __restrict__ xf, u8* __restrict__ mT_out,
                                              float* __restrict__ out, int bh0) {
  __shared__ __align__(16) u8 As[64*32];
  __shared__ __align__(16) u8 Bs[64*32];
  int t = threadIdx.x;
  int w = t >> 6, L = t & 63;
  int quad = L >> 4, l15 = L & 15;
  int bh_local = blockIdx.x >> 5;            // 32 i-tiles per bh
  int bh = bh0 + bh_local;
  int i0 = (blockIdx.x & 31) * 64;
  int b = bh >> 4, h = bh & (HEADS-1);
  const u8* abase = attn + (size_t)bh_local*SEQ*SEQ;
  const u8* mbase = mT_in + (size_t)bh*DH*SEQ;
  int srow = L >> 1, scol = (L & 1) * 16;    // 32 rows x 32B per wave-GLD16
  floatx4 acc[4];
#pragma unroll
  for (int j = 0; j < 4; j++) acc[j] = (floatx4){0.f,0.f,0.f,0.f};

  for (int j0 = 0; j0 < SEQ; j0 += 32) {
    if (w < 2)
      GLD16(abase + (size_t)(i0 + w*32 + srow)*SEQ + j0 + scol, &As[w*1024]);
    else
      GLD16(mbase + (size_t)((w-2)*32 + srow)*SEQ + j0 + scol, &Bs[(w-2)*1024]);
    __syncthreads();
    i64 af = *(const i64*)&As[(w*16 + l15)*32 + quad*8];
    i64 b0 = *(const i64*)&Bs[(l15)*32 + quad*8];
    i64 b1 = *(const i64*)&Bs[(16 + l15)*32 + quad*8];
    i64 b2 = *(const i64*)&Bs[(32 + l15)*32 + quad*8];
    i64 b3 = *(const i64*)&Bs[(48 + l15)*32 + quad*8];
    acc[0] = __builtin_amdgcn_mfma_f32_16x16x32_fp8_fp8(af, b0, acc[0], 0, 0, 0);
    acc[1] = __builtin_amdgcn_mfma_f32_16x16x32_fp8_fp8(af, b1, acc[1], 0, 0, 0);
    acc[2] = __builtin_amdgcn_mfma_f32_16x16x32_fp8_fp8(af, b2, acc[2], 0, 0, 0);
    acc[3] = __builtin_amdgcn_mfma_f32_16x16x32_fp8_fp8(af, b3, acc[3], 0, 0, 0);
    __syncthreads();
  }
  const float rs = 1.0f/256.0f;
  int ibase = i0 + w*16 + quad*4;
  float th[4][4]; float invr[4];
#pragma unroll
  for (int reg = 0; reg < 4; reg++) {
    size_t xoff = ((size_t)b*SEQ + ibase + reg)*NDIM + h*DH + l15;
    float s = 0.f;
#pragma unroll
    for (int nt = 0; nt < 4; nt++) {
      float v = acc[nt][reg]*rs + xf[xoff + nt*16];
      th[nt][reg] = v; s += v*v;
    }
    s += __shfl_xor(s, 1); s += __shfl_xor(s, 2); s += __shfl_xor(s, 4); s += __shfl_xor(s, 8);
    float tt2 = 0.5f*(1.0f + sqrtf(1.0f + s * INV_SCALE2));
    invr[reg] = 1.0f/(2.0f*tt2);
  }
  if (LAST) {
#pragma unroll
    for (int reg = 0; reg < 4; reg++) {
      size_t ooff = ((size_t)b*SEQ + ibase + reg)*NDIM + h*DH + l15;
#pragma unroll
      for (int nt = 0; nt < 4; nt++) out[ooff + nt*16] = th[nt][reg]*invr[reg];
    }
  } else {
#pragma unroll
    for (int nt = 0; nt < 4; nt++) {
      int p = pk4_fp8(th[nt][0]*invr[0], th[nt][1]*invr[1],
                      th[nt][2]*invr[2], th[nt][3]*invr[3]);
      *(int*)&mT_out[((size_t)bh*DH + nt*16 + l15)*SEQ + ibase] = p;
    }
  }
}

extern "C" void kernel_launch(void* const* d_in, const int* in_sizes, int n_in,
                              void* d_out, int out_size, void* d_ws, size_t ws_size,
                              hipStream_t stream) {
  const void* x    = d_in[0];
  const void* w_qk = d_in[1];
  const void* w1   = d_in[2];
  const void* w2   = d_in[3];
  float* out = (float*)d_out;

  const size_t E = (size_t)BQ*SEQ*NDIM;     // 4,194,304
  const int NW_QK = 2*NDIM*NDIM;
  const int NW1   = 4*NDIM*NDIM;
  const int NW2   = 4*NDIM*NDIM;

  char* ws = (char*)d_ws;
  size_t off = 0;
  auto alloc = [&](size_t bytes) { void* p = ws + off; off += (bytes + 255) & ~255ull; return p; };
  int*  flag = (int*)alloc(256);
  u16*  xs  = (u16*)alloc(E*2);             // scaled-normalized x (bf16)
  u16*  qb  = (u16*)alloc(E*2);             // q normalized [B,H,N,DH] bf16
  u16*  kb  = (u16*)alloc(E*2);
  float* xf = (float*)alloc(E*4);           // external field fp32
  u8*   mT  = (u8*)alloc(E*2);              // two fp8 m-buffers [B,H,DH,N]
  u8*   mTa = mT;
  u8*   mTb = mT + E;

  char* S = ws + off;
  size_t availS = (ws_size > off) ? ws_size - off : 0;
  // S-region temporal plan: [wqkb|qkraw] -> [.|.|w1b|w2b|hbuf] -> [attn chunk fp8]
  u16* wqkb  = (u16*)(S);
  u16* qkraw = (u16*)(S + 4194304);
  u16* w1b   = (u16*)(S + 20971520);
  u16* w2b   = (u16*)(S + 29360128);
  u16* hbuf  = (u16*)(S + 37748736);
  u8*  attn  = (u8*)(S);
  u16* xb    = (u16*)mT;                     // alias (2E bytes): dead before k_step0

  const int rcs[6] = {4096, 2048, 1024, 512, 256, 128};
  int RC = 0;
  for (int i = 0; i < 6; i++)
    if (37748736ull + (size_t)rcs[i]*4096*2 <= availS) { RC = rcs[i]; break; }
  const int chs[6] = {32, 16, 8, 4, 2, 1};
  int CH = 0;
  for (int i = 0; i < 6; i++)
    if ((size_t)chs[i]*SEQ*SEQ <= availS) { CH = chs[i]; break; }
  if (RC == 0 || CH == 0) {
    k_zero<<<(out_size+255)/256, 256, 0, stream>>>(out, out_size);
    return;
  }

  const int M = BQ*SEQ;  // 4096

  // dtype probe + canonical bf16 conversion
  k_flag0<<<1, 64, 0, stream>>>(flag);
  k_probe<<<256, 256, 0, stream>>>((const u16*)x, flag);
  k_convert<<<(int)(E/256), 256, 0, stream>>>(x, xb, flag, (int)E);
  k_convert<<<NW_QK/256, 256, 0, stream>>>(w_qk, wqkb, flag, NW_QK);
  k_convert<<<NW1/256, 256, 0, stream>>>(w1, w1b, flag, NW1);
  k_convert<<<NW2/256, 256, 0, stream>>>(w2, w2b, flag, NW2);

  k_norm_scale<<<M, 256, 0, stream>>>(xb, xs);
  { dim3 g(M/128, 2048/128); k_gemm<1,0,0><<<g, 256, 0, stream>>>(xs, wqkb, nullptr, qkraw, nullptr, M, 2048, 1024); }
  k_headnorm<<<M*HEADS, 64, 0, stream>>>(qkraw, qb, kb);

  for (int c = 0; c < M/RC; c++) {
    const u16* xsc = xs + (size_t)c*RC*NDIM;
    { dim3 g(RC/128, 4096/128); k_gemm<1,1,0><<<g, 256, 0, stream>>>(xsc, w1b, nullptr, hbuf, nullptr, RC, 4096, 1024); }
    { dim3 g(RC/128, 1024/128); k_gemm<0,0,1><<<g, 256, 0, stream>>>(hbuf, w2b, xf + (size_t)c*RC*NDIM, nullptr, xsc, RC, 1024, 4096); }
  }

  // step 0 closed form: m1 = mag(xf + m0v) since attn rows sum to 1 and m0 is constant
  float t0 = 0.5f*(1.0f + sqrtf(1.0f + 64.0f/511.0f));
  float m0v = 1.0f/(2.0f*t0);
  k_step0<<<BQ*HEADS*32, 256, 0, stream>>>(xf, mTa, m0v);

  for (int c0 = 0; c0 < BQ*HEADS; c0 += CH) {
    k_attn<<<CH*128, 256, 0, stream>>>(qb, kb, attn, c0);
    for (int s = 1; s < NSTEPS; s++) {
      u8* src = (s & 1) ? mTa : mTb;
      u8* dst = (s & 1) ? mTb : mTa;
      if (s == NSTEPS-1)
        k_step<1><<<CH*32, 256, 0, stream>>>(attn, src, xf, nullptr, out, c0);
      else
        k_step<0><<<CH*32, 256, 0, stream>>>(attn, src, xf, dst, nullptr, c0);
    }
  }
}